// Round 9
// baseline (126.070 us; speedup 1.0000x reference)
//
#include <hip/hip_runtime.h>
#include <hip/hip_bf16.h>

typedef unsigned short u16;
typedef __attribute__((ext_vector_type(8))) short bf16x8;
typedef __attribute__((ext_vector_type(4))) float f32x4;

#define L_SEQ 2048
#define HID 1024
#define NC 32
#define MTOK 4096
#define GEPS 1e-5f
#define QSCALE 0.125f

__device__ __forceinline__ float bf2f(u16 u){ union{unsigned i; float f;}c; c.i=(unsigned)u<<16; return c.f; }
__device__ __forceinline__ u16 f2bf(float f){ union{__hip_bfloat16 h; u16 u;}c; c.h=__float2bfloat16(f); return c.u; }

// transposed-LDS swizzle (rows 16 apart alias banks): XOR col bits 3..4 with row bits 4..5.
__device__ __forceinline__ int swz72(int row, int col){ return row * 72 + (col ^ ((row >> 1) & 24)); }
// C-fragment-shaped scatter swizzle
__device__ __forceinline__ int swzc(int t){ return ((t >> 2) & 3) << 3; }

__device__ __forceinline__ void gload_lds16(const u16* g, u16* l){
  __builtin_amdgcn_global_load_lds((const __attribute__((address_space(1))) void*)g,
                                   (__attribute__((address_space(3))) void*)l, 16, 0, 0);
}

// -------- prep: xb = bf16(x) + 5 weight transposes + xg1 = x @ Wg1 (MFMA), one grid -----
__global__ __launch_bounds__(256) void gla_prep(const float* __restrict__ x,
                                                u16* __restrict__ xb,
                                                const float* __restrict__ Wg1,
                                                float* __restrict__ xg1,
                                                const float* W0, const float* W1,
                                                const float* W2, const float* W3,
                                                const float* W4,
                                                u16* D0, u16* D1, u16* D2, u16* D3, u16* D4){
  __shared__ union { float tile[32][33]; u16 WL[16 * 1032]; } sh;
  int bid = blockIdx.x;
  if (bid < 2048){
    size_t i = ((size_t)bid * 256 + threadIdx.x) * 8;
    float4 a = *(const float4*)&x[i];
    float4 b = *(const float4*)&x[i + 4];
    u16 o[8] __attribute__((aligned(16))) = {
      f2bf(a.x), f2bf(a.y), f2bf(a.z), f2bf(a.w),
      f2bf(b.x), f2bf(b.y), f2bf(b.z), f2bf(b.w) };
    *(uint4*)&xb[i] = *(uint4*)o;
  } else if (bid < 7168){
    int id = bid - 2048;
    int z = id >> 10, rem = id & 1023;
    int bx = rem & 31, by = rem >> 5;
    const float* W; u16* D;
    switch (z){
      case 0: W = W0; D = D0; break;
      case 1: W = W1; D = D1; break;
      case 2: W = W2; D = D2; break;
      case 3: W = W3; D = D3; break;
      default: W = W4; D = D4; break;
    }
    int tx = threadIdx.x & 31, ty = threadIdx.x >> 5;
    int n0 = bx * 32, k0 = by * 32;
    #pragma unroll
    for (int r = ty; r < 32; r += 8)
      sh.tile[r][tx] = W[(size_t)(k0 + r) * HID + n0 + tx];
    __syncthreads();
    #pragma unroll
    for (int r = ty; r < 32; r += 8)
      D[(size_t)(n0 + r) * HID + k0 + tx] = f2bf(sh.tile[tx][r]);
  } else {
    // xg1 = x @ Wg1 via MFMA; reads x (f32) directly -> independent of xb blocks
    #pragma unroll 8
    for (int i = 0; i < 64; i++){
      int flat = i * 256 + threadIdx.x;
      int k = flat >> 4, n = flat & 15;
      sh.WL[n * 1032 + k] = f2bf(Wg1[flat]);
    }
    __syncthreads();
    int lane = threadIdx.x & 63, w = threadIdx.x >> 6;
    int lr = lane & 15, lk = lane >> 4;
    int rt = (bid - 7168) * 4 + w;        // row-tile 0..255
    const float* Arow = x + ((size_t)rt * 16 + lr) * HID;
    f32x4 acc;
    #pragma unroll
    for (int e = 0; e < 4; e++) acc[e] = 0.f;
    #pragma unroll 4
    for (int ks = 0; ks < 32; ks++){
      float4 a0 = *(const float4*)&Arow[ks * 32 + lk * 8];
      float4 a1 = *(const float4*)&Arow[ks * 32 + lk * 8 + 4];
      u16 av[8] __attribute__((aligned(16))) = {
        f2bf(a0.x), f2bf(a0.y), f2bf(a0.z), f2bf(a0.w),
        f2bf(a1.x), f2bf(a1.y), f2bf(a1.z), f2bf(a1.w) };
      bf16x8 a = *(bf16x8*)av;
      bf16x8 b = *(const bf16x8*)&sh.WL[lr * 1032 + ks * 32 + lk * 8];
      acc = __builtin_amdgcn_mfma_f32_16x16x32_bf16(a, b, acc, 0, 0, 0);
    }
    #pragma unroll
    for (int r = 0; r < 4; r++)
      xg1[(size_t)(rt * 16 + lk * 4 + r) * 16 + lr] = acc[r];
  }
}

// -------- gkcg v2: token-parallel z + two-level prefix scan; 1024 blocks ----------------
__global__ __launch_bounds__(256) void gla_gkcg2(const float* __restrict__ xg1,
                                                 const float* __restrict__ Wg2,
                                                 const float* __restrict__ bg2,
                                                 u16* __restrict__ CG){
  __shared__ float xs[64][17];
  __shared__ float wg[16][64];
  __shared__ float lss[64][65];
  __shared__ float red[4][64];
  int blk = blockIdx.x;                  // (b,c) 64 x colgroup 16
  int bc = blk >> 4, cgi = blk & 15;
  int b = bc >> 5, c = bc & 31;
  int col0 = cgi * 64;
  int tok0 = b * L_SEQ + c * 64;
  int tid = threadIdx.x;
  {
    int row = tid >> 2, e4 = (tid & 3) * 4;
    float4 v = *(const float4*)&xg1[(size_t)(tok0 + row) * 16 + e4];
    xs[row][e4 + 0] = v.x; xs[row][e4 + 1] = v.y;
    xs[row][e4 + 2] = v.z; xs[row][e4 + 3] = v.w;
    int f = tid * 4; int r = f >> 6, cc = f & 63;
    *(float4*)&wg[r][cc] = *(const float4*)&Wg2[(size_t)r * HID + col0 + cc];
  }
  __syncthreads();
  int t = tid & 63, cq = tid >> 6;
  float xr[16];
  #pragma unroll
  for (int r = 0; r < 16; r++) xr[r] = xs[t][r];
  #pragma unroll
  for (int i = 0; i < 16; i++){
    int col = cq * 16 + i;
    float z = bg2[col0 + col];
    #pragma unroll
    for (int r = 0; r < 16; r++) z += xr[r] * wg[r][col];
    lss[t][col] = -__logf(1.f + __expf(-z)) * (1.0f / 16.0f);
  }
  __syncthreads();
  // scan over t per column: local 16-step cumsum + cross-quarter offsets
  int col = tid & 63, q = tid >> 6;
  float cum16[16];
  float s = 0.f;
  #pragma unroll
  for (int i = 0; i < 16; i++){ s += lss[q * 16 + i][col]; cum16[i] = s; }
  red[q][col] = s;
  __syncthreads();
  float offs = 0.f;
  #pragma unroll
  for (int p = 0; p < 3; p++) if (p < q) offs += red[p][col];
  #pragma unroll
  for (int i = 0; i < 16; i++)
    CG[(size_t)(tok0 + q * 16 + i) * HID + col0 + col] = f2bf(offs + cum16[i]);
}

// ---------------- QKVG GEMM: 256x128 tile, 512 thr / 8 waves ----------------
__global__ __launch_bounds__(512) void gla_gemm_qkvg(const u16* __restrict__ A,
                                                     const u16* __restrict__ Bt,
                                                     u16* __restrict__ C){
  constexpr int NT = HID / 32;
  __shared__ u16 As[2][256 * 32];
  __shared__ u16 Bs[2][128 * 32];
  const int tid = threadIdx.x;
  const int lane = tid & 63, wid = tid >> 6;
  const int wm = wid >> 1, wn = wid & 1;
  const int lr = lane & 15, lk = lane >> 4;
  const int id = blockIdx.x + 16 * blockIdx.y;
  const int nid = (id & 7) * 64 + (id >> 3);
  const int bm = nid & 15, bn = nid >> 4;
  const int srow = tid >> 2;
  const int skw  = ((tid & 3) * 8) ^ ((srow & 3) << 3);
  const u16* Ag = A  + ((size_t)bm * 256 + srow) * HID + skw;
  const u16* Bg = Bt + ((size_t)bn * 128 + srow) * HID + skw;

  f32x4 acc[4][4];
  #pragma unroll
  for (int i = 0; i < 4; i++)
    #pragma unroll
    for (int j = 0; j < 4; j++)
      #pragma unroll
      for (int e = 0; e < 4; e++) acc[i][j][e] = 0.f;

  auto STAGE = [&](int buf, int kt){
    gload_lds16(Ag + kt * 32,                         &As[buf][tid * 8]);
    gload_lds16(Ag + (size_t)128 * HID + kt * 32,     &As[buf][4096 + tid * 8]);
    gload_lds16(Bg + kt * 32,                         &Bs[buf][tid * 8]);
  };

  STAGE(0, 0);
  for (int t = 0; t < NT; ++t){
    const int buf = t & 1;
    if (t + 1 < NT){
      STAGE(buf ^ 1, t + 1);
      asm volatile("s_waitcnt vmcnt(3)\ns_barrier" ::: "memory");
    } else {
      asm volatile("s_waitcnt vmcnt(0)\ns_barrier" ::: "memory");
    }
    bf16x8 af[4], bfr[4];
    #pragma unroll
    for (int m = 0; m < 4; m++){
      int row = wm * 64 + m * 16 + lr;
      af[m] = *(const bf16x8*)&As[buf][(row * 32 + lk * 8) ^ ((row & 3) << 3)];
    }
    #pragma unroll
    for (int n = 0; n < 4; n++){
      int row = wn * 64 + n * 16 + lr;
      bfr[n] = *(const bf16x8*)&Bs[buf][(row * 32 + lk * 8) ^ ((row & 3) << 3)];
    }
    __builtin_amdgcn_s_setprio(1);
    #pragma unroll
    for (int m = 0; m < 4; m++)
      #pragma unroll
      for (int n = 0; n < 4; n++)
        acc[m][n] = __builtin_amdgcn_mfma_f32_16x16x32_bf16(af[m], bfr[n], acc[m][n], 0, 0, 0);
    __builtin_amdgcn_s_setprio(0);
    __builtin_amdgcn_sched_barrier(0);
    asm volatile("s_barrier" ::: "memory");
  }

  #pragma unroll
  for (int i = 0; i < 4; i++)
    #pragma unroll
    for (int j = 0; j < 4; j++){
      int row0 = bm * 256 + wm * 64 + i * 16 + lk * 4;
      int cb   = bn * 128 + wn * 64 + j * 16 + lr;
      int sel  = cb >> 10, col = cb & 1023;
      size_t base = (size_t)sel * ((size_t)MTOK * HID) + (size_t)row0 * HID + col;
      #pragma unroll
      for (int r = 0; r < 4; r++)
        C[base + (size_t)r * HID] = f2bf(acc[i][j][r]);
    }
}

// ---------------- out GEMM v2: 64x128 tiles, 512 blocks, 256 thr, wave-pair split-K ------
__global__ __launch_bounds__(256) void gla_gemm_out2(const u16* __restrict__ A,
                                                     const u16* __restrict__ Bt,
                                                     float* __restrict__ C){
  constexpr int NT = 16;
  __shared__ __align__(16) char smem[49152];
  const int tid = threadIdx.x;
  const int lane = tid & 63, wid = tid >> 6;
  const int kg = wid >> 1, w = wid & 1;
  const int lr = lane & 15, lk = lane >> 4;
  const int bm = blockIdx.x, bn = blockIdx.y;
  const int srow = tid >> 2;
  const int skw  = ((tid & 3) * 8) ^ ((srow & 3) << 3);
  const u16* Ag = A  + ((size_t)bm * 64  + srow) * HID + skw;
  const u16* Bg = Bt + ((size_t)bn * 128 + srow) * HID + skw;
  auto seg = [&](int g, int buf) -> u16* { return (u16*)(smem + (g * 2 + buf) * 12288); };

  f32x4 acc[4][4];
  #pragma unroll
  for (int i = 0; i < 4; i++)
    #pragma unroll
    for (int j = 0; j < 4; j++)
      #pragma unroll
      for (int e = 0; e < 4; e++) acc[i][j][e] = 0.f;

  auto STAGE = [&](int buf, int kt){
    gload_lds16(Ag + kt * 32,                          seg(0, buf) + tid * 8);
    gload_lds16(Bg + kt * 32,                          seg(0, buf) + 2048 + tid * 8);
    gload_lds16(Bg + (size_t)64 * HID + kt * 32,       seg(0, buf) + 4096 + tid * 8);
    gload_lds16(Ag + 512 + kt * 32,                    seg(1, buf) + tid * 8);
    gload_lds16(Bg + 512 + kt * 32,                    seg(1, buf) + 2048 + tid * 8);
    gload_lds16(Bg + (size_t)64 * HID + 512 + kt * 32, seg(1, buf) + 4096 + tid * 8);
  };

  STAGE(0, 0);
  for (int t = 0; t < NT; ++t){
    const int buf = t & 1;
    if (t + 1 < NT){
      STAGE(buf ^ 1, t + 1);
      asm volatile("s_waitcnt vmcnt(6)\ns_barrier" ::: "memory");
    } else {
      asm volatile("s_waitcnt vmcnt(0)\ns_barrier" ::: "memory");
    }
    const u16* Ab = seg(kg, buf);
    const u16* Bb = seg(kg, buf) + 2048;
    bf16x8 af[4], bfr[4];
    #pragma unroll
    for (int m = 0; m < 4; m++){
      int row = m * 16 + lr;
      af[m] = *(const bf16x8*)&Ab[(row * 32 + lk * 8) ^ ((row & 3) << 3)];
    }
    #pragma unroll
    for (int n = 0; n < 4; n++){
      int row = w * 64 + n * 16 + lr;
      bfr[n] = *(const bf16x8*)&Bb[(row * 32 + lk * 8) ^ ((row & 3) << 3)];
    }
    __builtin_amdgcn_s_setprio(1);
    #pragma unroll
    for (int m = 0; m < 4; m++)
      #pragma unroll
      for (int n = 0; n < 4; n++)
        acc[m][n] = __builtin_amdgcn_mfma_f32_16x16x32_bf16(af[m], bfr[n], acc[m][n], 0, 0, 0);
    __builtin_amdgcn_s_setprio(0);
    __builtin_amdgcn_sched_barrier(0);
    asm volatile("s_barrier" ::: "memory");
  }

  float* red = (float*)smem;
  if (kg == 1){
    #pragma unroll
    for (int m = 0; m < 4; m++)
      #pragma unroll
      for (int n = 0; n < 4; n++){
        int lrow = m * 16 + lk * 4, lcol = w * 64 + n * 16 + lr;
        #pragma unroll
        for (int r = 0; r < 4; r++)
          red[(lrow + r) * 132 + lcol] = acc[m][n][r];
      }
  }
  __syncthreads();
  if (kg == 0){
    #pragma unroll
    for (int m = 0; m < 4; m++)
      #pragma unroll
      for (int n = 0; n < 4; n++){
        int lrow = m * 16 + lk * 4, lcol = w * 64 + n * 16 + lr;
        #pragma unroll
        for (int r = 0; r < 4; r++)
          C[(size_t)(bm * 64 + lrow + r) * HID + bn * 128 + lcol] =
              acc[m][n][r] + red[(lrow + r) * 132 + lcol];
      }
  }
}

// ---------------- pass B (MFMA): T_c = K^hat^T @ V (bf16 out), D_c = exp(cg_last) -------
__global__ __launch_bounds__(256) void gla_chunk_state2(const u16* __restrict__ Kb,
                                                        const u16* __restrict__ Vb,
                                                        const u16* __restrict__ CG,
                                                        u16* __restrict__ Tbuf,
                                                        float* __restrict__ Dbuf){
  __shared__ u16 KHT[64 * 72];
  __shared__ u16 VT[64 * 72];
  int blk = blockIdx.x;
  int c = blk & (NC - 1), bh = blk >> 5;
  int b = bh >> 4, h = bh & 15;
  int tid = threadIdx.x;
  int lane = tid & 63, w = tid >> 6;
  int lr = lane & 15, lk = lane >> 4;
  int tr = tid >> 2, tc = (tid & 3) * 16;
  size_t gbase = ((size_t)(b * L_SEQ + c * 64)) * HID + h * 64;

  float cg[16], cgl[16];
  {
    const u16* cgp = CG + gbase + (size_t)tr * HID + tc;
    const u16* clp = CG + gbase + (size_t)63 * HID + tc;
    uint4 a0 = *(const uint4*)cgp, a1 = *(const uint4*)(cgp + 8);
    uint4 l0 = *(const uint4*)clp, l1 = *(const uint4*)(clp + 8);
    const u16* au = (const u16*)&a0; const u16* au2 = (const u16*)&a1;
    const u16* lu = (const u16*)&l0; const u16* lu2 = (const u16*)&l1;
    #pragma unroll
    for (int e = 0; e < 8; e++){
      cg[e] = bf2f(au[e]); cg[8 + e] = bf2f(au2[e]);
      cgl[e] = bf2f(lu[e]); cgl[8 + e] = bf2f(lu2[e]);
    }
  }
  {
    const u16* kp = Kb + gbase + (size_t)tr * HID + tc;
    const u16* vp = Vb + gbase + (size_t)tr * HID + tc;
    uint4 kr0 = *(const uint4*)kp, kr1 = *(const uint4*)(kp + 8);
    uint4 vr0 = *(const uint4*)vp, vr1 = *(const uint4*)(vp + 8);
    const u16* ku = (const u16*)&kr0; const u16* ku2 = (const u16*)&kr1;
    const u16* vu = (const u16*)&vr0; const u16* vu2 = (const u16*)&vr1;
    #pragma unroll
    for (int e = 0; e < 8; e++){
      KHT[swz72(tc + e, tr)]     = f2bf(bf2f(ku[e])  * __expf(cgl[e]     - cg[e]));
      KHT[swz72(tc + 8 + e, tr)] = f2bf(bf2f(ku2[e]) * __expf(cgl[8 + e] - cg[8 + e]));
      VT[swz72(tc + e, tr)]      = vu[e];
      VT[swz72(tc + 8 + e, tr)]  = vu2[e];
    }
  }
  if (tr == 0){
    #pragma unroll
    for (int e = 0; e < 16; e++)
      Dbuf[(size_t)blk * 64 + tc + e] = __expf(cgl[e]);
  }
  __syncthreads();
  int R0 = w * 16;
  f32x4 tacc[4];
  #pragma unroll
  for (int v = 0; v < 4; v++)
    #pragma unroll
    for (int e = 0; e < 4; e++) tacc[v][e] = 0.f;
  #pragma unroll
  for (int ks = 0; ks < 2; ks++){
    bf16x8 a = *(const bf16x8*)&KHT[swz72(R0 + lr, ks * 32 + lk * 8)];
    #pragma unroll
    for (int v0 = 0; v0 < 4; v0++){
      bf16x8 bb = *(const bf16x8*)&VT[swz72(v0 * 16 + lr, ks * 32 + lk * 8)];
      tacc[v0] = __builtin_amdgcn_mfma_f32_16x16x32_bf16(a, bb, tacc[v0], 0, 0, 0);
    }
  }
  u16* Tp = Tbuf + (size_t)blk * 4096;
  #pragma unroll
  for (int v0 = 0; v0 < 4; v0++){
    int d = R0 + lk * 4, v = v0 * 16 + lr;
    #pragma unroll
    for (int r = 0; r < 4; r++)
      Tp[(d + r) * 64 + v] = f2bf(tacc[v0][r]);
  }
}

// ---------------- pass C v3: vectorized chunk-state scan (uint = 2 bf16 / thread) -------
__global__ __launch_bounds__(256) void gla_state_scan3(const u16* __restrict__ Tbuf,
                                                       const float* __restrict__ Dbuf,
                                                       float* __restrict__ Sfin,
                                                       u16* __restrict__ Sinb){
  int bh = blockIdx.x >> 3, seg = blockIdx.x & 7;
  int dv = seg * 512 + threadIdx.x * 2;
  int d = dv >> 6;
  float S0 = 0.f, S1 = 0.f;
  for (int c = 0; c < NC; c++){
    size_t slot = (size_t)bh * NC + c;
    unsigned tv = *(const unsigned*)&Tbuf[slot * 4096 + dv];
    float dec = Dbuf[slot * 64 + d];
    unsigned sv = (unsigned)f2bf(S0) | ((unsigned)f2bf(S1) << 16);
    *(unsigned*)&Sinb[slot * 4096 + dv] = sv;
    S0 = dec * S0 + bf2f((u16)(tv & 0xffff));
    S1 = dec * S1 + bf2f((u16)(tv >> 16));
  }
  float2 sf = make_float2(S0, S1);
  *(float2*)&Sfin[(size_t)bh * 4096 + dv] = sf;
}

// ---------------- pass D (MFMA): outputs + RMSNorm + swish gate (3-barrier) ----------
__global__ __launch_bounds__(256) void gla_chunk_out2(const u16* __restrict__ Qb,
                                                      const u16* __restrict__ Kb,
                                                      const u16* __restrict__ Vb,
                                                      const u16* __restrict__ CG,
                                                      const u16* __restrict__ Sinb,
                                                      const u16* __restrict__ Gb,
                                                      const float* __restrict__ gnw,
                                                      u16* __restrict__ OG){
  __shared__ u16 QT[64 * 72];
  __shared__ u16 KP[64 * 72];
  __shared__ u16 VT[64 * 72];
  __shared__ u16 ST[64 * 72];
  int blk = blockIdx.x;
  int c = blk & (NC - 1), bh = blk >> 5;
  int b = bh >> 4, h = bh & 15;
  int tid = threadIdx.x;
  int lane = tid & 63, w = tid >> 6;
  int lr = lane & 15, lk = lane >> 4;
  int tr = tid >> 2, tc = (tid & 3) * 16;
  size_t gbase = ((size_t)(b * L_SEQ + c * 64)) * HID + h * 64;

  {
    float cg[16];
    const u16* cgp = CG + gbase + (size_t)tr * HID + tc;
    uint4 a0 = *(const uint4*)cgp, a1 = *(const uint4*)(cgp + 8);
    const u16* au = (const u16*)&a0; const u16* au2 = (const u16*)&a1;
    #pragma unroll
    for (int e = 0; e < 8; e++){ cg[e] = bf2f(au[e]); cg[8 + e] = bf2f(au2[e]); }
    const u16* qp = Qb + gbase + (size_t)tr * HID + tc;
    const u16* kp = Kb + gbase + (size_t)tr * HID + tc;
    const u16* vp = Vb + gbase + (size_t)tr * HID + tc;
    uint4 qr0 = *(const uint4*)qp, qr1 = *(const uint4*)(qp + 8);
    uint4 kr0 = *(const uint4*)kp, kr1 = *(const uint4*)(kp + 8);
    uint4 vr0 = *(const uint4*)vp, vr1 = *(const uint4*)(vp + 8);
    const u16* qu = (const u16*)&qr0; const u16* qu2 = (const u16*)&qr1;
    const u16* ku = (const u16*)&kr0; const u16* ku2 = (const u16*)&kr1;
    const u16* vu = (const u16*)&vr0; const u16* vu2 = (const u16*)&vr1;
    u16 qt[16] __attribute__((aligned(16)));
    u16 kt[16] __attribute__((aligned(16)));
    #pragma unroll
    for (int e = 0; e < 8; e++){
      float ec0 = __expf(cg[e]),  ei0 = __expf(-cg[e]);
      float ec1 = __expf(cg[8+e]), ei1 = __expf(-cg[8+e]);
      qt[e]     = f2bf(bf2f(qu[e])  * ec0 * QSCALE);
      qt[8 + e] = f2bf(bf2f(qu2[e]) * ec1 * QSCALE);
      kt[e]     = f2bf(bf2f(ku[e])  * ei0);
      kt[8 + e] = f2bf(bf2f(ku2[e]) * ei1);
      VT[swz72(tc + e, tr)]     = vu[e];
      VT[swz72(tc + 8 + e, tr)] = vu2[e];
    }
    *(uint4*)&QT[tr * 72 + tc]     = *(uint4*)&qt[0];
    *(uint4*)&QT[tr * 72 + tc + 8] = *(uint4*)&qt[8];
    *(uint4*)&KP[tr * 72 + tc]     = *(uint4*)&kt[0];
    *(uint4*)&KP[tr * 72 + tc + 8] = *(uint4*)&kt[8];
    const u16* sp = Sinb + (size_t)blk * 4096 + (size_t)tr * 64 + tc;
    uint4 s0 = *(const uint4*)sp, s1 = *(const uint4*)(sp + 8);
    const u16* su = (const u16*)&s0; const u16* su2 = (const u16*)&s1;
    #pragma unroll
    for (int e = 0; e < 8; e++){
      ST[swz72(tc + e, tr)]     = su[e];
      ST[swz72(tc + 8 + e, tr)] = su2[e];
    }
  }
  __syncthreads();

  int R0 = w * 16;
  f32x4 pacc[4];
  #pragma unroll
  for (int j = 0; j < 4; j++)
    #pragma unroll
    for (int e = 0; e < 4; e++) pacc[j][e] = 0.f;
  #pragma unroll
  for (int ks = 0; ks < 2; ks++){
    bf16x8 a = *(const bf16x8*)&QT[(R0 + lr) * 72 + ks * 32 + lk * 8];
    #pragma unroll
    for (int j0 = 0; j0 < 4; j0++){
      bf16x8 bb = *(const bf16x8*)&KP[(j0 * 16 + lr) * 72 + ks * 32 + lk * 8];
      pacc[j0] = __builtin_amdgcn_mfma_f32_16x16x32_bf16(a, bb, pacc[j0], 0, 0, 0);
    }
  }
  __syncthreads();

  #pragma unroll
  for (int j0 = 0; j0 < 4; j0++){
    int j = j0 * 16 + lr;
    #pragma unroll
    for (int r = 0; r < 4; r++){
      int t = R0 + lk * 4 + r;
      KP[t * 72 + (j ^ swzc(t))] = (j <= t) ? f2bf(pacc[j0][r]) : (u16)0;
    }
  }

  f32x4 oacc[4];
  #pragma unroll
  for (int v = 0; v < 4; v++)
    #pragma unroll
    for (int e = 0; e < 4; e++) oacc[v][e] = 0.f;
  #pragma unroll
  for (int ks = 0; ks < 2; ks++){
    bf16x8 a = *(const bf16x8*)&QT[(R0 + lr) * 72 + ks * 32 + lk * 8];
    #pragma unroll
    for (int v0 = 0; v0 < 4; v0++){
      bf16x8 bb = *(const bf16x8*)&ST[swz72(v0 * 16 + lr, ks * 32 + lk * 8)];
      oacc[v0] = __builtin_amdgcn_mfma_f32_16x16x32_bf16(a, bb, oacc[v0], 0, 0, 0);
    }
  }
  #pragma unroll
  for (int ks = 0; ks < 2; ks++){
    int arow = R0 + lr;
    bf16x8 a = *(const bf16x8*)&KP[arow * 72 + ((ks * 32 + lk * 8) ^ swzc(arow))];
    #pragma unroll
    for (int v0 = 0; v0 < 4; v0++){
      bf16x8 bb = *(const bf16x8*)&VT[swz72(v0 * 16 + lr, ks * 32 + lk * 8)];
      oacc[v0] = __builtin_amdgcn_mfma_f32_16x16x32_bf16(a, bb, oacc[v0], 0, 0, 0);
    }
  }

  {
    float gv[4][4];
    #pragma unroll
    for (int r = 0; r < 4; r++){
      int t = R0 + lk * 4 + r;
      #pragma unroll
      for (int v0 = 0; v0 < 4; v0++)
        gv[r][v0] = bf2f(Gb[gbase + (size_t)t * HID + v0 * 16 + lr]);
    }
    float gnv[4];
    #pragma unroll
    for (int v0 = 0; v0 < 4; v0++) gnv[v0] = gnw[v0 * 16 + lr];
    #pragma unroll
    for (int r = 0; r < 4; r++){
      float ssq = 0.f;
      #pragma unroll
      for (int v0 = 0; v0 < 4; v0++) ssq += oacc[v0][r] * oacc[v0][r];
      ssq += __shfl_xor(ssq, 1, 64);
      ssq += __shfl_xor(ssq, 2, 64);
      ssq += __shfl_xor(ssq, 4, 64);
      ssq += __shfl_xor(ssq, 8, 64);
      float rn = rsqrtf(ssq * (1.0f / 64.0f) + GEPS);
      int t = R0 + lk * 4 + r;
      #pragma unroll
      for (int v0 = 0; v0 < 4; v0++){
        float g = gv[r][v0];
        float sw = g / (1.f + __expf(-g));
        QT[t * 72 + ((v0 * 16 + lr) ^ swzc(t))] = f2bf(oacc[v0][r] * rn * gnv[v0] * sw);
      }
    }
  }
  __syncthreads();
  {
    int x0 = swzc(tr);
    uint4 o0 = *(uint4*)&QT[tr * 72 + (tc ^ x0)];
    uint4 o1 = *(uint4*)&QT[tr * 72 + ((tc + 8) ^ x0)];
    u16* op = OG + gbase + (size_t)tr * HID + tc;
    *(uint4*)op       = o0;
    *(uint4*)(op + 8) = o1;
  }
}

// ---------------- host launcher ----------------
extern "C" void kernel_launch(void* const* d_in, const int* in_sizes, int n_in,
                              void* d_out, int out_size, void* d_ws, size_t ws_size,
                              hipStream_t stream){
  (void)in_sizes; (void)n_in; (void)out_size;
  const float* x   = (const float*)d_in[0];
  const float* Wq  = (const float*)d_in[1];
  const float* Wk  = (const float*)d_in[2];
  const float* Wv  = (const float*)d_in[3];
  const float* Wg1 = (const float*)d_in[4];
  const float* Wg2 = (const float*)d_in[5];
  const float* bg2 = (const float*)d_in[6];
  const float* Wg  = (const float*)d_in[7];
  const float* gnw = (const float*)d_in[8];
  const float* Wo  = (const float*)d_in[9];
  float* out = (float*)d_out;

  char* ws = (char*)d_ws;
  size_t off = 0;
  auto alloc = [&](size_t bytes) -> char* {
    char* p = ws + off; off += (bytes + 255) & ~(size_t)255; return p;
  };
  u16* xb   = (u16*)alloc((size_t)MTOK * HID * 2);
  u16* WTq  = (u16*)alloc((size_t)HID * HID * 2);   // WTq..WTg contiguous: combined N=4096
  u16* WTk  = (u16*)alloc((size_t)HID * HID * 2);
  u16* WTv  = (u16*)alloc((size_t)HID * HID * 2);
  u16* WTg  = (u16*)alloc((size_t)HID * HID * 2);
  u16* WTo  = (u16*)alloc((size_t)HID * HID * 2);
  u16* Qb   = (u16*)alloc((size_t)MTOK * HID * 2);  // Qb..Gb contiguous: sel-strided C
  u16* Kb   = (u16*)alloc((size_t)MTOK * HID * 2);
  u16* Vb   = (u16*)alloc((size_t)MTOK * HID * 2);
  u16* Gb   = (u16*)alloc((size_t)MTOK * HID * 2);
  u16* CGb  = (u16*)alloc((size_t)MTOK * HID * 2);
  float* xg1b = (float*)alloc((size_t)MTOK * 16 * 4);
  u16* Tbuf = (u16*)alloc((size_t)1024 * 4096 * 2);
  float* Dbuf = (float*)alloc((size_t)1024 * 64 * 4);
  u16* Sinb = (u16*)alloc((size_t)1024 * 4096 * 2);
  u16* OG   = (u16*)alloc((size_t)MTOK * HID * 2);
  if (off > ws_size) return;

  gla_prep<<<7232, 256, 0, stream>>>(x, xb, Wg1, xg1b, Wq, Wk, Wv, Wg, Wo,
                                     WTq, WTk, WTv, WTg, WTo);
  gla_gkcg2<<<1024, 256, 0, stream>>>(xg1b, Wg2, bg2, CGb);

  dim3 gq(16, 32);
  gla_gemm_qkvg<<<gq, 512, 0, stream>>>(xb, WTq, Qb);   // Q,K,V,G in one dispatch

  gla_chunk_state2<<<1024, 256, 0, stream>>>(Kb, Vb, CGb, Tbuf, Dbuf);
  gla_state_scan3<<<256, 256, 0, stream>>>(Tbuf, Dbuf, out + (size_t)MTOK * HID, Sinb);
  gla_chunk_out2<<<1024, 256, 0, stream>>>(Qb, Kb, Vb, CGb, Sinb, Gb, gnw, OG);

  dim3 go(64, 8);
  gla_gemm_out2<<<go, 256, 0, stream>>>(OG, WTo, out);
}

// Round 10
// 115.692 us; speedup vs baseline: 1.0897x; 1.0897x over previous
//
#include <hip/hip_runtime.h>
#include <hip/hip_bf16.h>

typedef unsigned short u16;
typedef __attribute__((ext_vector_type(8))) short bf16x8;
typedef __attribute__((ext_vector_type(4))) float f32x4;

#define L_SEQ 2048
#define HID 1024
#define NC 32
#define MTOK 4096
#define GEPS 1e-5f
#define QSCALE 0.125f

__device__ __forceinline__ float bf2f(u16 u){ union{unsigned i; float f;}c; c.i=(unsigned)u<<16; return c.f; }
__device__ __forceinline__ u16 f2bf(float f){ union{__hip_bfloat16 h; u16 u;}c; c.h=__float2bfloat16(f); return c.u; }

// transposed-LDS swizzle (rows 16 apart alias banks): XOR col bits 3..4 with row bits 4..5.
__device__ __forceinline__ int swz72(int row, int col){ return row * 72 + (col ^ ((row >> 1) & 24)); }
// C-fragment-shaped scatter swizzle
__device__ __forceinline__ int swzc(int t){ return ((t >> 2) & 3) << 3; }

__device__ __forceinline__ void gload_lds16(const u16* g, u16* l){
  __builtin_amdgcn_global_load_lds((const __attribute__((address_space(1))) void*)g,
                                   (__attribute__((address_space(3))) void*)l, 16, 0, 0);
}

// ---------------- prep: xb = bf16(x) (streaming) + 5 weight transposes ----------------
__global__ __launch_bounds__(256) void gla_prep(const float* __restrict__ x,
                                                u16* __restrict__ xb,
                                                const float* W0, const float* W1,
                                                const float* W2, const float* W3,
                                                const float* W4,
                                                u16* D0, u16* D1, u16* D2, u16* D3, u16* D4){
  __shared__ float tile[32][33];
  int bid = blockIdx.x;
  if (bid < 2048){
    size_t i = ((size_t)bid * 256 + threadIdx.x) * 8;
    float4 a = *(const float4*)&x[i];
    float4 b = *(const float4*)&x[i + 4];
    u16 o[8] __attribute__((aligned(16))) = {
      f2bf(a.x), f2bf(a.y), f2bf(a.z), f2bf(a.w),
      f2bf(b.x), f2bf(b.y), f2bf(b.z), f2bf(b.w) };
    *(uint4*)&xb[i] = *(uint4*)o;
  } else {
    int id = bid - 2048;
    int z = id >> 10, rem = id & 1023;
    int bx = rem & 31, by = rem >> 5;
    const float* W; u16* D;
    switch (z){
      case 0: W = W0; D = D0; break;
      case 1: W = W1; D = D1; break;
      case 2: W = W2; D = D2; break;
      case 3: W = W3; D = D3; break;
      default: W = W4; D = D4; break;
    }
    int tx = threadIdx.x & 31, ty = threadIdx.x >> 5;
    int n0 = bx * 32, k0 = by * 32;
    #pragma unroll
    for (int r = ty; r < 32; r += 8)
      tile[r][tx] = W[(size_t)(k0 + r) * HID + n0 + tx];
    __syncthreads();
    #pragma unroll
    for (int r = ty; r < 32; r += 8)
      D[(size_t)(n0 + r) * HID + k0 + tx] = f2bf(tile[tx][r]);
  }
}

// ---------------- xg1 = xb @ Wg1 via MFMA (4096x16x1024) ----------------
__global__ __launch_bounds__(256) void gla_xg1_mfma(const u16* __restrict__ xb,
                                                    const float* __restrict__ Wg1,
                                                    float* __restrict__ xg1){
  __shared__ u16 WL[16 * 1032];
  #pragma unroll 8
  for (int i = 0; i < 64; i++){
    int flat = i * 256 + threadIdx.x;
    int k = flat >> 4, n = flat & 15;
    WL[n * 1032 + k] = f2bf(Wg1[flat]);
  }
  __syncthreads();
  int lane = threadIdx.x & 63, w = threadIdx.x >> 6;
  int lr = lane & 15, lk = lane >> 4;
  int rt = blockIdx.x * 4 + w;
  const u16* Arow = xb + ((size_t)rt * 16 + lr) * HID;
  f32x4 acc;
  #pragma unroll
  for (int e = 0; e < 4; e++) acc[e] = 0.f;
  #pragma unroll 4
  for (int ks = 0; ks < 32; ks++){
    bf16x8 a = *(const bf16x8*)&Arow[ks * 32 + lk * 8];
    bf16x8 b = *(const bf16x8*)&WL[lr * 1032 + ks * 32 + lk * 8];
    acc = __builtin_amdgcn_mfma_f32_16x16x32_bf16(a, b, acc, 0, 0, 0);
  }
  #pragma unroll
  for (int r = 0; r < 4; r++)
    xg1[(size_t)(rt * 16 + lk * 4 + r) * 16 + lr] = acc[r];
}

// -------- gkcg v2: token-parallel z + two-level prefix scan; 1024 blocks ----------------
__global__ __launch_bounds__(256) void gla_gkcg2(const float* __restrict__ xg1,
                                                 const float* __restrict__ Wg2,
                                                 const float* __restrict__ bg2,
                                                 u16* __restrict__ CG){
  __shared__ float xs[64][17];
  __shared__ float wg[16][64];
  __shared__ float lss[64][65];
  __shared__ float red[4][64];
  int blk = blockIdx.x;
  int bc = blk >> 4, cgi = blk & 15;
  int b = bc >> 5, c = bc & 31;
  int col0 = cgi * 64;
  int tok0 = b * L_SEQ + c * 64;
  int tid = threadIdx.x;
  {
    int row = tid >> 2, e4 = (tid & 3) * 4;
    float4 v = *(const float4*)&xg1[(size_t)(tok0 + row) * 16 + e4];
    xs[row][e4 + 0] = v.x; xs[row][e4 + 1] = v.y;
    xs[row][e4 + 2] = v.z; xs[row][e4 + 3] = v.w;
    int f = tid * 4; int r = f >> 6, cc = f & 63;
    *(float4*)&wg[r][cc] = *(const float4*)&Wg2[(size_t)r * HID + col0 + cc];
  }
  __syncthreads();
  int t = tid & 63, cq = tid >> 6;
  float xr[16];
  #pragma unroll
  for (int r = 0; r < 16; r++) xr[r] = xs[t][r];
  #pragma unroll
  for (int i = 0; i < 16; i++){
    int col = cq * 16 + i;
    float z = bg2[col0 + col];
    #pragma unroll
    for (int r = 0; r < 16; r++) z += xr[r] * wg[r][col];
    lss[t][col] = -__logf(1.f + __expf(-z)) * (1.0f / 16.0f);
  }
  __syncthreads();
  int col = tid & 63, q = tid >> 6;
  float cum16[16];
  float s = 0.f;
  #pragma unroll
  for (int i = 0; i < 16; i++){ s += lss[q * 16 + i][col]; cum16[i] = s; }
  red[q][col] = s;
  __syncthreads();
  float offs = 0.f;
  #pragma unroll
  for (int p = 0; p < 3; p++) if (p < q) offs += red[p][col];
  #pragma unroll
  for (int i = 0; i < 16; i++)
    CG[(size_t)(tok0 + q * 16 + i) * HID + col0 + col] = f2bf(offs + cum16[i]);
}

// ---------------- QKVG GEMM: 256x128 tile, 512 thr / 8 waves ----------------
__global__ __launch_bounds__(512) void gla_gemm_qkvg(const u16* __restrict__ A,
                                                     const u16* __restrict__ Bt,
                                                     u16* __restrict__ C){
  constexpr int NT = HID / 32;
  __shared__ u16 As[2][256 * 32];
  __shared__ u16 Bs[2][128 * 32];
  const int tid = threadIdx.x;
  const int lane = tid & 63, wid = tid >> 6;
  const int wm = wid >> 1, wn = wid & 1;
  const int lr = lane & 15, lk = lane >> 4;
  const int id = blockIdx.x + 16 * blockIdx.y;
  const int nid = (id & 7) * 64 + (id >> 3);
  const int bm = nid & 15, bn = nid >> 4;
  const int srow = tid >> 2;
  const int skw  = ((tid & 3) * 8) ^ ((srow & 3) << 3);
  const u16* Ag = A  + ((size_t)bm * 256 + srow) * HID + skw;
  const u16* Bg = Bt + ((size_t)bn * 128 + srow) * HID + skw;

  f32x4 acc[4][4];
  #pragma unroll
  for (int i = 0; i < 4; i++)
    #pragma unroll
    for (int j = 0; j < 4; j++)
      #pragma unroll
      for (int e = 0; e < 4; e++) acc[i][j][e] = 0.f;

  auto STAGE = [&](int buf, int kt){
    gload_lds16(Ag + kt * 32,                         &As[buf][tid * 8]);
    gload_lds16(Ag + (size_t)128 * HID + kt * 32,     &As[buf][4096 + tid * 8]);
    gload_lds16(Bg + kt * 32,                         &Bs[buf][tid * 8]);
  };

  STAGE(0, 0);
  for (int t = 0; t < NT; ++t){
    const int buf = t & 1;
    if (t + 1 < NT){
      STAGE(buf ^ 1, t + 1);
      asm volatile("s_waitcnt vmcnt(3)\ns_barrier" ::: "memory");
    } else {
      asm volatile("s_waitcnt vmcnt(0)\ns_barrier" ::: "memory");
    }
    bf16x8 af[4], bfr[4];
    #pragma unroll
    for (int m = 0; m < 4; m++){
      int row = wm * 64 + m * 16 + lr;
      af[m] = *(const bf16x8*)&As[buf][(row * 32 + lk * 8) ^ ((row & 3) << 3)];
    }
    #pragma unroll
    for (int n = 0; n < 4; n++){
      int row = wn * 64 + n * 16 + lr;
      bfr[n] = *(const bf16x8*)&Bs[buf][(row * 32 + lk * 8) ^ ((row & 3) << 3)];
    }
    __builtin_amdgcn_s_setprio(1);
    #pragma unroll
    for (int m = 0; m < 4; m++)
      #pragma unroll
      for (int n = 0; n < 4; n++)
        acc[m][n] = __builtin_amdgcn_mfma_f32_16x16x32_bf16(af[m], bfr[n], acc[m][n], 0, 0, 0);
    __builtin_amdgcn_s_setprio(0);
    __builtin_amdgcn_sched_barrier(0);
    asm volatile("s_barrier" ::: "memory");
  }

  #pragma unroll
  for (int i = 0; i < 4; i++)
    #pragma unroll
    for (int j = 0; j < 4; j++){
      int row0 = bm * 256 + wm * 64 + i * 16 + lk * 4;
      int cb   = bn * 128 + wn * 64 + j * 16 + lr;
      int sel  = cb >> 10, col = cb & 1023;
      size_t base = (size_t)sel * ((size_t)MTOK * HID) + (size_t)row0 * HID + col;
      #pragma unroll
      for (int r = 0; r < 4; r++)
        C[base + (size_t)r * HID] = f2bf(acc[i][j][r]);
    }
}

// ---------------- out GEMM v2: 64x128 tiles, 512 blocks, 256 thr, wave-pair split-K ------
__global__ __launch_bounds__(256) void gla_gemm_out2(const u16* __restrict__ A,
                                                     const u16* __restrict__ Bt,
                                                     float* __restrict__ C){
  constexpr int NT = 16;
  __shared__ __align__(16) char smem[49152];
  const int tid = threadIdx.x;
  const int lane = tid & 63, wid = tid >> 6;
  const int kg = wid >> 1, w = wid & 1;
  const int lr = lane & 15, lk = lane >> 4;
  const int bm = blockIdx.x, bn = blockIdx.y;
  const int srow = tid >> 2;
  const int skw  = ((tid & 3) * 8) ^ ((srow & 3) << 3);
  const u16* Ag = A  + ((size_t)bm * 64  + srow) * HID + skw;
  const u16* Bg = Bt + ((size_t)bn * 128 + srow) * HID + skw;
  auto seg = [&](int g, int buf) -> u16* { return (u16*)(smem + (g * 2 + buf) * 12288); };

  f32x4 acc[4][4];
  #pragma unroll
  for (int i = 0; i < 4; i++)
    #pragma unroll
    for (int j = 0; j < 4; j++)
      #pragma unroll
      for (int e = 0; e < 4; e++) acc[i][j][e] = 0.f;

  auto STAGE = [&](int buf, int kt){
    gload_lds16(Ag + kt * 32,                          seg(0, buf) + tid * 8);
    gload_lds16(Bg + kt * 32,                          seg(0, buf) + 2048 + tid * 8);
    gload_lds16(Bg + (size_t)64 * HID + kt * 32,       seg(0, buf) + 4096 + tid * 8);
    gload_lds16(Ag + 512 + kt * 32,                    seg(1, buf) + tid * 8);
    gload_lds16(Bg + 512 + kt * 32,                    seg(1, buf) + 2048 + tid * 8);
    gload_lds16(Bg + (size_t)64 * HID + 512 + kt * 32, seg(1, buf) + 4096 + tid * 8);
  };

  STAGE(0, 0);
  for (int t = 0; t < NT; ++t){
    const int buf = t & 1;
    if (t + 1 < NT){
      STAGE(buf ^ 1, t + 1);
      asm volatile("s_waitcnt vmcnt(6)\ns_barrier" ::: "memory");
    } else {
      asm volatile("s_waitcnt vmcnt(0)\ns_barrier" ::: "memory");
    }
    const u16* Ab = seg(kg, buf);
    const u16* Bb = seg(kg, buf) + 2048;
    bf16x8 af[4], bfr[4];
    #pragma unroll
    for (int m = 0; m < 4; m++){
      int row = m * 16 + lr;
      af[m] = *(const bf16x8*)&Ab[(row * 32 + lk * 8) ^ ((row & 3) << 3)];
    }
    #pragma unroll
    for (int n = 0; n < 4; n++){
      int row = w * 64 + n * 16 + lr;
      bfr[n] = *(const bf16x8*)&Bb[(row * 32 + lk * 8) ^ ((row & 3) << 3)];
    }
    __builtin_amdgcn_s_setprio(1);
    #pragma unroll
    for (int m = 0; m < 4; m++)
      #pragma unroll
      for (int n = 0; n < 4; n++)
        acc[m][n] = __builtin_amdgcn_mfma_f32_16x16x32_bf16(af[m], bfr[n], acc[m][n], 0, 0, 0);
    __builtin_amdgcn_s_setprio(0);
    __builtin_amdgcn_sched_barrier(0);
    asm volatile("s_barrier" ::: "memory");
  }

  float* red = (float*)smem;
  if (kg == 1){
    #pragma unroll
    for (int m = 0; m < 4; m++)
      #pragma unroll
      for (int n = 0; n < 4; n++){
        int lrow = m * 16 + lk * 4, lcol = w * 64 + n * 16 + lr;
        #pragma unroll
        for (int r = 0; r < 4; r++)
          red[(lrow + r) * 132 + lcol] = acc[m][n][r];
      }
  }
  __syncthreads();
  if (kg == 0){
    #pragma unroll
    for (int m = 0; m < 4; m++)
      #pragma unroll
      for (int n = 0; n < 4; n++){
        int lrow = m * 16 + lk * 4, lcol = w * 64 + n * 16 + lr;
        #pragma unroll
        for (int r = 0; r < 4; r++)
          C[(size_t)(bm * 64 + lrow + r) * HID + bn * 128 + lcol] =
              acc[m][n][r] + red[(lrow + r) * 132 + lcol];
      }
  }
}

// ---------------- pass B (MFMA): T_c = K^hat^T @ V (bf16 out), D_c = exp(cg_last) -------
__global__ __launch_bounds__(256) void gla_chunk_state2(const u16* __restrict__ Kb,
                                                        const u16* __restrict__ Vb,
                                                        const u16* __restrict__ CG,
                                                        u16* __restrict__ Tbuf,
                                                        float* __restrict__ Dbuf){
  __shared__ u16 KHT[64 * 72];
  __shared__ u16 VT[64 * 72];
  int blk = blockIdx.x;
  int c = blk & (NC - 1), bh = blk >> 5;
  int b = bh >> 4, h = bh & 15;
  int tid = threadIdx.x;
  int lane = tid & 63, w = tid >> 6;
  int lr = lane & 15, lk = lane >> 4;
  int tr = tid >> 2, tc = (tid & 3) * 16;
  size_t gbase = ((size_t)(b * L_SEQ + c * 64)) * HID + h * 64;

  float cg[16], cgl[16];
  {
    const u16* cgp = CG + gbase + (size_t)tr * HID + tc;
    const u16* clp = CG + gbase + (size_t)63 * HID + tc;
    uint4 a0 = *(const uint4*)cgp, a1 = *(const uint4*)(cgp + 8);
    uint4 l0 = *(const uint4*)clp, l1 = *(const uint4*)(clp + 8);
    const u16* au = (const u16*)&a0; const u16* au2 = (const u16*)&a1;
    const u16* lu = (const u16*)&l0; const u16* lu2 = (const u16*)&l1;
    #pragma unroll
    for (int e = 0; e < 8; e++){
      cg[e] = bf2f(au[e]); cg[8 + e] = bf2f(au2[e]);
      cgl[e] = bf2f(lu[e]); cgl[8 + e] = bf2f(lu2[e]);
    }
  }
  {
    const u16* kp = Kb + gbase + (size_t)tr * HID + tc;
    const u16* vp = Vb + gbase + (size_t)tr * HID + tc;
    uint4 kr0 = *(const uint4*)kp, kr1 = *(const uint4*)(kp + 8);
    uint4 vr0 = *(const uint4*)vp, vr1 = *(const uint4*)(vp + 8);
    const u16* ku = (const u16*)&kr0; const u16* ku2 = (const u16*)&kr1;
    const u16* vu = (const u16*)&vr0; const u16* vu2 = (const u16*)&vr1;
    #pragma unroll
    for (int e = 0; e < 8; e++){
      KHT[swz72(tc + e, tr)]     = f2bf(bf2f(ku[e])  * __expf(cgl[e]     - cg[e]));
      KHT[swz72(tc + 8 + e, tr)] = f2bf(bf2f(ku2[e]) * __expf(cgl[8 + e] - cg[8 + e]));
      VT[swz72(tc + e, tr)]      = vu[e];
      VT[swz72(tc + 8 + e, tr)]  = vu2[e];
    }
  }
  if (tr == 0){
    #pragma unroll
    for (int e = 0; e < 16; e++)
      Dbuf[(size_t)blk * 64 + tc + e] = __expf(cgl[e]);
  }
  __syncthreads();
  int R0 = w * 16;
  f32x4 tacc[4];
  #pragma unroll
  for (int v = 0; v < 4; v++)
    #pragma unroll
    for (int e = 0; e < 4; e++) tacc[v][e] = 0.f;
  #pragma unroll
  for (int ks = 0; ks < 2; ks++){
    bf16x8 a = *(const bf16x8*)&KHT[swz72(R0 + lr, ks * 32 + lk * 8)];
    #pragma unroll
    for (int v0 = 0; v0 < 4; v0++){
      bf16x8 bb = *(const bf16x8*)&VT[swz72(v0 * 16 + lr, ks * 32 + lk * 8)];
      tacc[v0] = __builtin_amdgcn_mfma_f32_16x16x32_bf16(a, bb, tacc[v0], 0, 0, 0);
    }
  }
  u16* Tp = Tbuf + (size_t)blk * 4096;
  #pragma unroll
  for (int v0 = 0; v0 < 4; v0++){
    int d = R0 + lk * 4, v = v0 * 16 + lr;
    #pragma unroll
    for (int r = 0; r < 4; r++)
      Tp[(d + r) * 64 + v] = f2bf(tacc[v0][r]);
  }
}

// ---------------- pass C: parallel chunk-state scan (bf16 T in, bf16 S_in out) ----------
__global__ __launch_bounds__(256) void gla_state_scan2(const u16* __restrict__ Tbuf,
                                                       const float* __restrict__ Dbuf,
                                                       float* __restrict__ Sfin,
                                                       u16* __restrict__ Sinb){
  int bh = blockIdx.x >> 4, seg = blockIdx.x & 15;
  int dv = seg * 256 + threadIdx.x;
  int d = dv >> 6;
  float S = 0.f;
  for (int c = 0; c < NC; c++){
    size_t slot = (size_t)bh * NC + c;
    float t  = bf2f(Tbuf[slot * 4096 + dv]);
    float dec = Dbuf[slot * 64 + d];
    Sinb[slot * 4096 + dv] = f2bf(S);
    S = dec * S + t;
  }
  Sfin[(size_t)bh * 4096 + dv] = S;
}

// ---------------- pass D (MFMA): outputs + RMSNorm + swish gate (3-barrier) ----------
__global__ __launch_bounds__(256) void gla_chunk_out2(const u16* __restrict__ Qb,
                                                      const u16* __restrict__ Kb,
                                                      const u16* __restrict__ Vb,
                                                      const u16* __restrict__ CG,
                                                      const u16* __restrict__ Sinb,
                                                      const u16* __restrict__ Gb,
                                                      const float* __restrict__ gnw,
                                                      u16* __restrict__ OG){
  __shared__ u16 QT[64 * 72];
  __shared__ u16 KP[64 * 72];
  __shared__ u16 VT[64 * 72];
  __shared__ u16 ST[64 * 72];
  int blk = blockIdx.x;
  int c = blk & (NC - 1), bh = blk >> 5;
  int b = bh >> 4, h = bh & 15;
  int tid = threadIdx.x;
  int lane = tid & 63, w = tid >> 6;
  int lr = lane & 15, lk = lane >> 4;
  int tr = tid >> 2, tc = (tid & 3) * 16;
  size_t gbase = ((size_t)(b * L_SEQ + c * 64)) * HID + h * 64;

  {
    float cg[16];
    const u16* cgp = CG + gbase + (size_t)tr * HID + tc;
    uint4 a0 = *(const uint4*)cgp, a1 = *(const uint4*)(cgp + 8);
    const u16* au = (const u16*)&a0; const u16* au2 = (const u16*)&a1;
    #pragma unroll
    for (int e = 0; e < 8; e++){ cg[e] = bf2f(au[e]); cg[8 + e] = bf2f(au2[e]); }
    const u16* qp = Qb + gbase + (size_t)tr * HID + tc;
    const u16* kp = Kb + gbase + (size_t)tr * HID + tc;
    const u16* vp = Vb + gbase + (size_t)tr * HID + tc;
    uint4 qr0 = *(const uint4*)qp, qr1 = *(const uint4*)(qp + 8);
    uint4 kr0 = *(const uint4*)kp, kr1 = *(const uint4*)(kp + 8);
    uint4 vr0 = *(const uint4*)vp, vr1 = *(const uint4*)(vp + 8);
    const u16* qu = (const u16*)&qr0; const u16* qu2 = (const u16*)&qr1;
    const u16* ku = (const u16*)&kr0; const u16* ku2 = (const u16*)&kr1;
    const u16* vu = (const u16*)&vr0; const u16* vu2 = (const u16*)&vr1;
    u16 qt[16] __attribute__((aligned(16)));
    u16 kt[16] __attribute__((aligned(16)));
    #pragma unroll
    for (int e = 0; e < 8; e++){
      float ec0 = __expf(cg[e]),  ei0 = __expf(-cg[e]);
      float ec1 = __expf(cg[8+e]), ei1 = __expf(-cg[8+e]);
      qt[e]     = f2bf(bf2f(qu[e])  * ec0 * QSCALE);
      qt[8 + e] = f2bf(bf2f(qu2[e]) * ec1 * QSCALE);
      kt[e]     = f2bf(bf2f(ku[e])  * ei0);
      kt[8 + e] = f2bf(bf2f(ku2[e]) * ei1);
      VT[swz72(tc + e, tr)]     = vu[e];
      VT[swz72(tc + 8 + e, tr)] = vu2[e];
    }
    *(uint4*)&QT[tr * 72 + tc]     = *(uint4*)&qt[0];
    *(uint4*)&QT[tr * 72 + tc + 8] = *(uint4*)&qt[8];
    *(uint4*)&KP[tr * 72 + tc]     = *(uint4*)&kt[0];
    *(uint4*)&KP[tr * 72 + tc + 8] = *(uint4*)&kt[8];
    const u16* sp = Sinb + (size_t)blk * 4096 + (size_t)tr * 64 + tc;
    uint4 s0 = *(const uint4*)sp, s1 = *(const uint4*)(sp + 8);
    const u16* su = (const u16*)&s0; const u16* su2 = (const u16*)&s1;
    #pragma unroll
    for (int e = 0; e < 8; e++){
      ST[swz72(tc + e, tr)]     = su[e];
      ST[swz72(tc + 8 + e, tr)] = su2[e];
    }
  }
  __syncthreads();

  int R0 = w * 16;
  f32x4 pacc[4];
  #pragma unroll
  for (int j = 0; j < 4; j++)
    #pragma unroll
    for (int e = 0; e < 4; e++) pacc[j][e] = 0.f;
  #pragma unroll
  for (int ks = 0; ks < 2; ks++){
    bf16x8 a = *(const bf16x8*)&QT[(R0 + lr) * 72 + ks * 32 + lk * 8];
    #pragma unroll
    for (int j0 = 0; j0 < 4; j0++){
      bf16x8 bb = *(const bf16x8*)&KP[(j0 * 16 + lr) * 72 + ks * 32 + lk * 8];
      pacc[j0] = __builtin_amdgcn_mfma_f32_16x16x32_bf16(a, bb, pacc[j0], 0, 0, 0);
    }
  }
  __syncthreads();

  #pragma unroll
  for (int j0 = 0; j0 < 4; j0++){
    int j = j0 * 16 + lr;
    #pragma unroll
    for (int r = 0; r < 4; r++){
      int t = R0 + lk * 4 + r;
      KP[t * 72 + (j ^ swzc(t))] = (j <= t) ? f2bf(pacc[j0][r]) : (u16)0;
    }
  }

  f32x4 oacc[4];
  #pragma unroll
  for (int v = 0; v < 4; v++)
    #pragma unroll
    for (int e = 0; e < 4; e++) oacc[v][e] = 0.f;
  #pragma unroll
  for (int ks = 0; ks < 2; ks++){
    bf16x8 a = *(const bf16x8*)&QT[(R0 + lr) * 72 + ks * 32 + lk * 8];
    #pragma unroll
    for (int v0 = 0; v0 < 4; v0++){
      bf16x8 bb = *(const bf16x8*)&ST[swz72(v0 * 16 + lr, ks * 32 + lk * 8)];
      oacc[v0] = __builtin_amdgcn_mfma_f32_16x16x32_bf16(a, bb, oacc[v0], 0, 0, 0);
    }
  }
  #pragma unroll
  for (int ks = 0; ks < 2; ks++){
    int arow = R0 + lr;
    bf16x8 a = *(const bf16x8*)&KP[arow * 72 + ((ks * 32 + lk * 8) ^ swzc(arow))];
    #pragma unroll
    for (int v0 = 0; v0 < 4; v0++){
      bf16x8 bb = *(const bf16x8*)&VT[swz72(v0 * 16 + lr, ks * 32 + lk * 8)];
      oacc[v0] = __builtin_amdgcn_mfma_f32_16x16x32_bf16(a, bb, oacc[v0], 0, 0, 0);
    }
  }

  {
    float gv[4][4];
    #pragma unroll
    for (int r = 0; r < 4; r++){
      int t = R0 + lk * 4 + r;
      #pragma unroll
      for (int v0 = 0; v0 < 4; v0++)
        gv[r][v0] = bf2f(Gb[gbase + (size_t)t * HID + v0 * 16 + lr]);
    }
    float gnv[4];
    #pragma unroll
    for (int v0 = 0; v0 < 4; v0++) gnv[v0] = gnw[v0 * 16 + lr];
    #pragma unroll
    for (int r = 0; r < 4; r++){
      float ssq = 0.f;
      #pragma unroll
      for (int v0 = 0; v0 < 4; v0++) ssq += oacc[v0][r] * oacc[v0][r];
      ssq += __shfl_xor(ssq, 1, 64);
      ssq += __shfl_xor(ssq, 2, 64);
      ssq += __shfl_xor(ssq, 4, 64);
      ssq += __shfl_xor(ssq, 8, 64);
      float rn = rsqrtf(ssq * (1.0f / 64.0f) + GEPS);
      int t = R0 + lk * 4 + r;
      #pragma unroll
      for (int v0 = 0; v0 < 4; v0++){
        float g = gv[r][v0];
        float sw = g / (1.f + __expf(-g));
        QT[t * 72 + ((v0 * 16 + lr) ^ swzc(t))] = f2bf(oacc[v0][r] * rn * gnv[v0] * sw);
      }
    }
  }
  __syncthreads();
  {
    int x0 = swzc(tr);
    uint4 o0 = *(uint4*)&QT[tr * 72 + (tc ^ x0)];
    uint4 o1 = *(uint4*)&QT[tr * 72 + ((tc + 8) ^ x0)];
    u16* op = OG + gbase + (size_t)tr * HID + tc;
    *(uint4*)op       = o0;
    *(uint4*)(op + 8) = o1;
  }
}

// ---------------- host launcher ----------------
extern "C" void kernel_launch(void* const* d_in, const int* in_sizes, int n_in,
                              void* d_out, int out_size, void* d_ws, size_t ws_size,
                              hipStream_t stream){
  (void)in_sizes; (void)n_in; (void)out_size;
  const float* x   = (const float*)d_in[0];
  const float* Wq  = (const float*)d_in[1];
  const float* Wk  = (const float*)d_in[2];
  const float* Wv  = (const float*)d_in[3];
  const float* Wg1 = (const float*)d_in[4];
  const float* Wg2 = (const float*)d_in[5];
  const float* bg2 = (const float*)d_in[6];
  const float* Wg  = (const float*)d_in[7];
  const float* gnw = (const float*)d_in[8];
  const float* Wo  = (const float*)d_in[9];
  float* out = (float*)d_out;

  char* ws = (char*)d_ws;
  size_t off = 0;
  auto alloc = [&](size_t bytes) -> char* {
    char* p = ws + off; off += (bytes + 255) & ~(size_t)255; return p;
  };
  u16* xb   = (u16*)alloc((size_t)MTOK * HID * 2);
  u16* WTq  = (u16*)alloc((size_t)HID * HID * 2);   // WTq..WTg contiguous: combined N=4096
  u16* WTk  = (u16*)alloc((size_t)HID * HID * 2);
  u16* WTv  = (u16*)alloc((size_t)HID * HID * 2);
  u16* WTg  = (u16*)alloc((size_t)HID * HID * 2);
  u16* WTo  = (u16*)alloc((size_t)HID * HID * 2);
  u16* Qb   = (u16*)alloc((size_t)MTOK * HID * 2);  // Qb..Gb contiguous: sel-strided C
  u16* Kb   = (u16*)alloc((size_t)MTOK * HID * 2);
  u16* Vb   = (u16*)alloc((size_t)MTOK * HID * 2);
  u16* Gb   = (u16*)alloc((size_t)MTOK * HID * 2);
  u16* CGb  = (u16*)alloc((size_t)MTOK * HID * 2);
  float* xg1b = (float*)alloc((size_t)MTOK * 16 * 4);
  u16* Tbuf = (u16*)alloc((size_t)1024 * 4096 * 2);
  float* Dbuf = (float*)alloc((size_t)1024 * 64 * 4);
  u16* Sinb = (u16*)alloc((size_t)1024 * 4096 * 2);
  u16* OG   = (u16*)alloc((size_t)MTOK * HID * 2);
  if (off > ws_size) return;

  gla_prep<<<7168, 256, 0, stream>>>(x, xb, Wq, Wk, Wv, Wg, Wo,
                                     WTq, WTk, WTv, WTg, WTo);
  gla_xg1_mfma<<<64, 256, 0, stream>>>(xb, Wg1, xg1b);
  gla_gkcg2<<<1024, 256, 0, stream>>>(xg1b, Wg2, bg2, CGb);

  dim3 gq(16, 32);
  gla_gemm_qkvg<<<gq, 512, 0, stream>>>(xb, WTq, Qb);   // Q,K,V,G in one dispatch

  gla_chunk_state2<<<1024, 256, 0, stream>>>(Kb, Vb, CGb, Tbuf, Dbuf);
  gla_state_scan2<<<512, 256, 0, stream>>>(Tbuf, Dbuf, out + (size_t)MTOK * HID, Sinb);
  gla_chunk_out2<<<1024, 256, 0, stream>>>(Qb, Kb, Vb, CGb, Sinb, Gb, gnw, OG);

  dim3 go(64, 8);
  gla_gemm_out2<<<go, 256, 0, stream>>>(OG, WTo, out);
}